// Round 6
// baseline (255.721 us; speedup 1.0000x reference)
//
#include <hip/hip_runtime.h>
#include <float.h>
#include <math.h>

#define BB 32
#define NN 1024
#define DD 128
#define KK 5

typedef __attribute__((ext_vector_type(8))) short bf16x8;
typedef __attribute__((ext_vector_type(4))) float f32x4;
typedef unsigned long long ull;

// rtne f32->bf16 bit trick (no NaN/inf in this problem)
__device__ __forceinline__ unsigned short f2bf(float f) {
    unsigned int u = __float_as_uint(f);
    return (unsigned short)((u + 0x7FFFu + ((u >> 16) & 1u)) >> 16);
}
__device__ __forceinline__ float bf2f(unsigned short h) {
    return __uint_as_float(((unsigned int)h) << 16);
}

// packed sortable key: (orderable(v) << 32) | (1023 - col)
// u64 max == lexicographic (value desc, col asc) == lax.top_k order.
__device__ __forceinline__ ull mkkey(float v, int col) {
    unsigned int u = __float_as_uint(v);
    unsigned int ou = u ^ (unsigned)((((int)u) >> 31) | 0x80000000);
    return ((ull)ou << 32) | (unsigned)(1023 - col);
}

// branchless sorted-5 insert (s[0] >= s[1] >= ... >= s[4])
__device__ __forceinline__ void ins5(ull k, ull* s) {
    bool b0 = k > s[0], b1 = k > s[1], b2 = k > s[2], b3 = k > s[3], b4 = k > s[4];
    s[4] = b4 ? (b3 ? s[3] : k) : s[4];
    s[3] = b3 ? (b2 ? s[2] : k) : s[3];
    s[2] = b2 ? (b1 ? s[1] : k) : s[2];
    s[1] = b1 ? (b0 ? s[0] : k) : s[1];
    s[0] = b0 ? k : s[0];
}

// ---- 1. fused: row L2-normalize + 3-limb bf16 split (h,m,l planes) ------
__global__ __launch_bounds__(256) void k_norm(const float* __restrict__ x,
                                              unsigned short* __restrict__ ph,
                                              unsigned short* __restrict__ pm,
                                              unsigned short* __restrict__ pl) {
    int row  = blockIdx.x * 4 + (threadIdx.x >> 6);
    int lane = threadIdx.x & 63;
    float2 v = *reinterpret_cast<const float2*>(x + (size_t)row * DD + lane * 2);
    float ss = v.x * v.x + v.y * v.y;
#pragma unroll
    for (int o = 32; o >= 1; o >>= 1) ss += __shfl_xor(ss, o);
    float inv = 1.0f / fmaxf(sqrtf(ss), 1e-12f);
    float y0 = v.x * inv, y1 = v.y * inv;

    unsigned short h0 = f2bf(y0);             float r0 = y0 - bf2f(h0);
    unsigned short m0 = f2bf(r0);             float s0 = r0 - bf2f(m0);
    unsigned short l0 = f2bf(s0);
    unsigned short h1 = f2bf(y1);             float r1 = y1 - bf2f(h1);
    unsigned short m1 = f2bf(r1);             float s1 = r1 - bf2f(m1);
    unsigned short l1 = f2bf(s1);

    size_t o = (size_t)row * DD + lane * 2;
    *reinterpret_cast<unsigned int*>(ph + o) = (unsigned int)h0 | ((unsigned int)h1 << 16);
    *reinterpret_cast<unsigned int*>(pm + o) = (unsigned int)m0 | ((unsigned int)m1 << 16);
    *reinterpret_cast<unsigned int*>(pl + o) = (unsigned int)l0 | ((unsigned int)l1 << 16);
}

union SMem {
    struct {
        unsigned short Ah[128][40], Am[128][40], Al[128][40];
        unsigned short Bh[128][40], Bm[128][40], Bl[128][40];
    } s;                      // 61440 B (MFMA staging)
    float q[4][32][68];       // 34816 B (per-wave extraction scratch)
};

__device__ __forceinline__ void stage_plane(const unsigned short* __restrict__ g,
                                            unsigned short (*s)[40], int tid,
                                            size_t rowbase, int c) {
#pragma unroll
    for (int hh = 0; hh < 2; ++hh) {
        int u = tid + (hh << 8);
        int row = u >> 2, qq = u & 3;
        const float4 v = *reinterpret_cast<const float4*>(
            g + (rowbase + row) * DD + (c << 5) + (qq << 3));
        *reinterpret_cast<float4*>(&s[row][qq << 3]) = v;
    }
}

// ---- 2. sim tile + fused per-segment top-5 candidates (no sim matrix) ---
__global__ __launch_bounds__(256, 2) void k_sim(const unsigned short* __restrict__ ph,
                                                const unsigned short* __restrict__ pm,
                                                const unsigned short* __restrict__ pl,
                                                ull* __restrict__ cand) {
    // XCD-chunked bijective swizzle: 1152 = 8 * 144; 144 = 4 batches * 36
    int bid = blockIdx.x;
    int lb  = (bid & 7) * 144 + (bid >> 3);
    int bl  = lb / 36;
    int p   = lb - bl * 36;
    int ti = 0;
    while (p >= 8 - ti) { p -= 8 - ti; ++ti; }
    int tj = ti + p;
    int R  = ti << 7, Cc = tj << 7;

    __shared__ SMem sm;

    int tid  = threadIdx.x;
    int wv   = tid >> 6;
    int lane = tid & 63;
    int wr = (wv >> 1) << 6;
    int wc = (wv & 1) << 6;
    int lg = lane >> 4, fr = lane & 15;

    size_t base = (size_t)bl * NN;
    size_t rbA = base + R, rbB = base + Cc;

    f32x4 acc[4][4];
#pragma unroll
    for (int i = 0; i < 4; ++i)
#pragma unroll
        for (int j = 0; j < 4; ++j) acc[i][j] = (f32x4){0.f, 0.f, 0.f, 0.f};

    int kk = lg << 3;   // k-offset within chunk for fragments

    for (int c = 0; c < 4; ++c) {
        if (c) __syncthreads();
        stage_plane(ph, sm.s.Ah, tid, rbA, c);
        stage_plane(pm, sm.s.Am, tid, rbA, c);
        stage_plane(pl, sm.s.Al, tid, rbA, c);
        stage_plane(ph, sm.s.Bh, tid, rbB, c);
        stage_plane(pm, sm.s.Bm, tid, rbB, c);
        stage_plane(pl, sm.s.Bl, tid, rbB, c);
        __syncthreads();

        bf16x8 bh[4], bm[4], blo[4];
#pragma unroll
        for (int cp = 0; cp < 4; ++cp) {
            int rb = wc + cp * 16 + fr;
            bh[cp]  = *reinterpret_cast<const bf16x8*>(&sm.s.Bh[rb][kk]);
            bm[cp]  = *reinterpret_cast<const bf16x8*>(&sm.s.Bm[rb][kk]);
            blo[cp] = *reinterpret_cast<const bf16x8*>(&sm.s.Bl[rb][kk]);
        }
#pragma unroll
        for (int rp = 0; rp < 4; ++rp) {
            int ra = wr + rp * 16 + fr;
            bf16x8 ah = *reinterpret_cast<const bf16x8*>(&sm.s.Ah[ra][kk]);
            bf16x8 am = *reinterpret_cast<const bf16x8*>(&sm.s.Am[ra][kk]);
            bf16x8 al = *reinterpret_cast<const bf16x8*>(&sm.s.Al[ra][kk]);
#pragma unroll
            for (int cp = 0; cp < 4; ++cp) {
                f32x4 cacc = acc[rp][cp];
                cacc = __builtin_amdgcn_mfma_f32_16x16x32_bf16(ah, bh[cp],  cacc, 0, 0, 0);
                cacc = __builtin_amdgcn_mfma_f32_16x16x32_bf16(ah, bm[cp],  cacc, 0, 0, 0);
                cacc = __builtin_amdgcn_mfma_f32_16x16x32_bf16(am, bh[cp],  cacc, 0, 0, 0);
                cacc = __builtin_amdgcn_mfma_f32_16x16x32_bf16(ah, blo[cp], cacc, 0, 0, 0);
                cacc = __builtin_amdgcn_mfma_f32_16x16x32_bf16(al, bh[cp],  cacc, 0, 0, 0);
                cacc = __builtin_amdgcn_mfma_f32_16x16x32_bf16(am, bm[cp],  cacc, 0, 0, 0);
                acc[rp][cp] = cacc;
            }
        }
    }

    __syncthreads();   // staging LDS dead -> safe to reuse union as q[]

    // ---- row segments: LDS transpose, lane = row, stream 64 cols --------
    ull s5[5] = {0, 0, 0, 0, 0};
    int grow = R + wr + lane;                 // this lane's global row
#pragma unroll
    for (int hp = 0; hp < 2; ++hp) {
        // write acc cols [32hp, 32hp+32): acc[rp][cp] is 4 consecutive rows
#pragma unroll
        for (int rp = 0; rp < 4; ++rp)
#pragma unroll
            for (int cpl = 0; cpl < 2; ++cpl) {
                int cp = 2 * hp + cpl;
                *reinterpret_cast<float4*>(&sm.q[wv][cpl * 16 + fr][rp * 16 + lg * 4]) =
                    *reinterpret_cast<float4*>(&acc[rp][cp]);
            }
        // read own row (conflict-free: consecutive lanes consecutive addr)
#pragma unroll
        for (int c = 0; c < 32; ++c) {
            float v = sm.q[wv][c][lane];
            int gc = Cc + wc + 32 * hp + c;
            ull key = mkkey(v, gc);
            if (gc == grow) key = 0;          // diagonal mask
            ins5(key, s5);
        }
    }
    {
        int slot = 2 * tj + (wc >> 6);
        ull* o = cand + ((base + grow) * 16 + slot) * 5;
        o[0] = s5[0]; o[1] = s5[1]; o[2] = s5[2]; o[3] = s5[3]; o[4] = s5[4];
    }

    // ---- mirror segments (cols as rows), straight from registers --------
    if (ti != tj) {
        int slot = 2 * ti + (wr >> 6);
#pragma unroll
        for (int cp = 0; cp < 4; ++cp) {
            ull m5[5] = {0, 0, 0, 0, 0};
#pragma unroll
            for (int rp = 0; rp < 4; ++rp)
#pragma unroll
                for (int rg = 0; rg < 4; ++rg) {
                    int gr2 = R + wr + rp * 16 + lg * 4 + rg;  // neighbor idx
                    ins5(mkkey(acc[rp][cp][rg], gr2), m5);
                }
            int mnode = Cc + wc + cp * 16 + fr;
            ull* o = cand + ((base + mnode) * 16 + slot) * 5;
            ull k0 = m5[0], k1 = m5[1], k2 = m5[2], k3 = m5[3], k4 = m5[4];
#pragma unroll
            for (int t = 0; t < 5; ++t) {
                ull w = k0;
                ull x = __shfl_xor(w, 16); if (x > w) w = x;
                x     = __shfl_xor(w, 32); if (x > w) w = x;
                if (lg == 0) o[t] = w;
                bool adv = (k0 == w);
                k0 = adv ? k1 : k0; k1 = adv ? k2 : k1;
                k2 = adv ? k3 : k2; k3 = adv ? k4 : k3; k4 = adv ? 0ULL : k4;
            }
        }
    }
}

// ---- 3. merge: global top-5 of 16 slots x 5 sorted keys per row ---------
__global__ __launch_bounds__(256) void k_merge(const ull* __restrict__ cand,
                                               int* __restrict__ idx) {
    int row = blockIdx.x * 16 + (threadIdx.x >> 4);
    int g   = threadIdx.x & 15;
    const ull* cp = cand + ((size_t)row * 16 + g) * 5;
    ull k0 = cp[0], k1 = cp[1], k2 = cp[2], k3 = cp[3], k4 = cp[4];
    int* op = idx + (size_t)row * KK;
#pragma unroll
    for (int t = 0; t < 5; ++t) {
        ull w = k0;
#pragma unroll
        for (int o = 1; o < 16; o <<= 1) {    // xor<16 stays in 16-group
            ull x = __shfl_xor(w, o); if (x > w) w = x;
        }
        if (g == t) op[t] = 1023 - (int)(w & 0xFFFFFFFFu);
        bool adv = (k0 == w);
        k0 = adv ? k1 : k0; k1 = adv ? k2 : k1;
        k2 = adv ? k3 : k2; k3 = adv ? k4 : k3; k4 = adv ? 0ULL : k4;
    }
}

// ---- 4. fused gcn: out = res + relu( agg(h,idx) @ W^T + bias ) ----------
#define SW(c) ((c) + 4 * ((c) >> 5))
#define LDW 140

__global__ __launch_bounds__(256, 3) void k_gcn(const float* __restrict__ h,
                                                const int* __restrict__ idx,
                                                const float* __restrict__ W,
                                                const float* __restrict__ bias,
                                                const float* __restrict__ res,
                                                float* __restrict__ out) {
    int rt = blockIdx.x << 6;
    __shared__ float As[64][68];
    __shared__ float Bs[64][LDW];
    int tid = threadIdx.x;
    int tr  = (tid >> 4) << 2;
    int tc  = (tid & 15) << 3;
    int stc = SW(tc);

    float acc[4][8];
#pragma unroll
    for (int i = 0; i < 4; ++i)
#pragma unroll
        for (int j = 0; j < 8; ++j) acc[i][j] = 0.f;

#pragma unroll
    for (int kc = 0; kc < 2; ++kc) {
        if (kc) __syncthreads();
        {
            int kv = tid & 15, r0 = tid >> 4;
            int colf = (kc << 6) + (kv << 2);
#pragma unroll
            for (int pq = 0; pq < 4; ++pq) {
                int lrow = r0 + (pq << 4);
                int grow = rt + lrow;
                const int* ip = idx + (size_t)grow * KK;
                const float* hb = h + (((size_t)grow >> 10) << 10) * DD;
                float4 v = *reinterpret_cast<const float4*>(h + (size_t)grow * DD + colf);
#pragma unroll
                for (int t = 0; t < KK; ++t) {
                    const float4 u = *reinterpret_cast<const float4*>(hb + (size_t)ip[t] * DD + colf);
                    v.x += u.x; v.y += u.y; v.z += u.z; v.w += u.w;
                }
                const float c = 1.0f / 6.0f;
                int k = kv << 2;
                As[k + 0][lrow] = v.x * c; As[k + 1][lrow] = v.y * c;
                As[k + 2][lrow] = v.z * c; As[k + 3][lrow] = v.w * c;
            }
        }
        {
            int kv = tid & 15, r0 = tid >> 4;
            const float* g = W + kc * 64;
#pragma unroll
            for (int pq = 0; pq < 8; ++pq) {
                int r = r0 + (pq << 4);
                const float4 v = *reinterpret_cast<const float4*>(g + (size_t)r * DD + (kv << 2));
                int k = kv << 2, row = SW(r);
                Bs[k + 0][row] = v.x; Bs[k + 1][row] = v.y;
                Bs[k + 2][row] = v.z; Bs[k + 3][row] = v.w;
            }
        }
        __syncthreads();
#pragma unroll 4
        for (int k = 0; k < 64; ++k) {
            const float4 a  = *reinterpret_cast<const float4*>(&As[k][tr]);
            const float4 b0 = *reinterpret_cast<const float4*>(&Bs[k][stc]);
            const float4 b1 = *reinterpret_cast<const float4*>(&Bs[k][stc + 4]);
            const float av[4] = {a.x, a.y, a.z, a.w};
            const float bw[8] = {b0.x, b0.y, b0.z, b0.w, b1.x, b1.y, b1.z, b1.w};
#pragma unroll
            for (int ii = 0; ii < 4; ++ii)
#pragma unroll
                for (int jj = 0; jj < 8; ++jj)
                    acc[ii][jj] = fmaf(av[ii], bw[jj], acc[ii][jj]);
        }
    }
    const float4 bz0 = *reinterpret_cast<const float4*>(bias + tc);
    const float4 bz1 = *reinterpret_cast<const float4*>(bias + tc + 4);
    const float bb[8] = {bz0.x, bz0.y, bz0.z, bz0.w, bz1.x, bz1.y, bz1.z, bz1.w};
#pragma unroll
    for (int i = 0; i < 4; ++i) {
        size_t ro = (size_t)(rt + tr + i) * DD + tc;
        const float4 r0 = *reinterpret_cast<const float4*>(res + ro);
        const float4 r1 = *reinterpret_cast<const float4*>(res + ro + 4);
        float4 o0, o1;
        o0.x = r0.x + fmaxf(acc[i][0] + bb[0], 0.f);
        o0.y = r0.y + fmaxf(acc[i][1] + bb[1], 0.f);
        o0.z = r0.z + fmaxf(acc[i][2] + bb[2], 0.f);
        o0.w = r0.w + fmaxf(acc[i][3] + bb[3], 0.f);
        o1.x = r1.x + fmaxf(acc[i][4] + bb[4], 0.f);
        o1.y = r1.y + fmaxf(acc[i][5] + bb[5], 0.f);
        o1.z = r1.z + fmaxf(acc[i][6] + bb[6], 0.f);
        o1.w = r1.w + fmaxf(acc[i][7] + bb[7], 0.f);
        *reinterpret_cast<float4*>(out + ro)     = o0;
        *reinterpret_cast<float4*>(out + ro + 4) = o1;
    }
}

extern "C" void kernel_launch(void* const* d_in, const int* in_sizes, int n_in,
                              void* d_out, int out_size, void* d_ws, size_t ws_size,
                              hipStream_t stream) {
    const float* x  = (const float*)d_in[0];
    const float* W1 = (const float*)d_in[1];
    const float* b1 = (const float*)d_in[2];
    const float* W2 = (const float*)d_in[3];
    const float* b2 = (const float*)d_in[4];
    float* out = (float*)d_out;

    char* ws = (char*)d_ws;
    size_t pl_b   = (size_t)BB * NN * DD * 2;          // bf16 plane
    size_t h1_b   = (size_t)BB * NN * DD * 4;
    size_t idx_b  = (size_t)BB * NN * KK * 4;
    size_t cand_b = (size_t)BB * NN * 16 * 5 * 8;      // 21 MB
    unsigned short* ph = (unsigned short*)ws;  ws += pl_b;
    unsigned short* pm = (unsigned short*)ws;  ws += pl_b;
    unsigned short* pl = (unsigned short*)ws;  ws += pl_b;
    float* h1  = (float*)ws;                   ws += h1_b;
    int*   idx = (int*)ws;                     ws += idx_b;
    ull*  cand = (ull*)ws;                     ws += cand_b;

    k_norm<<<BB * NN / 4, 256, 0, stream>>>(x, ph, pm, pl);
    k_sim<<<BB * 36, 256, 0, stream>>>(ph, pm, pl, cand);
    k_merge<<<BB * NN / 16, 256, 0, stream>>>(cand, idx);
    k_gcn<<<BB * NN / 64, 256, 0, stream>>>(x,  idx, W1, b1, x,  h1);
    k_gcn<<<BB * NN / 64, 256, 0, stream>>>(h1, idx, W2, b2, h1, out);
}

// Round 7
// 156.553 us; speedup vs baseline: 1.6334x; 1.6334x over previous
//
#include <hip/hip_runtime.h>
#include <float.h>
#include <math.h>

#define BB 32
#define NN 1024
#define DD 128
#define KK 5

typedef __attribute__((ext_vector_type(8))) short bf16x8;
typedef __attribute__((ext_vector_type(4))) float f32x4;

// rtne f32->bf16 bit trick (no NaN/inf in this problem)
__device__ __forceinline__ unsigned short f2bf(float f) {
    unsigned int u = __float_as_uint(f);
    return (unsigned short)((u + 0x7FFFu + ((u >> 16) & 1u)) >> 16);
}
__device__ __forceinline__ float bf2f(unsigned short h) {
    return __uint_as_float(((unsigned int)h) << 16);
}

// ---- 1. fused: row L2-normalize + 3-limb bf16 split (h,m,l planes) ------
__global__ __launch_bounds__(256) void k_norm(const float* __restrict__ x,
                                              unsigned short* __restrict__ ph,
                                              unsigned short* __restrict__ pm,
                                              unsigned short* __restrict__ pl) {
    int row  = blockIdx.x * 4 + (threadIdx.x >> 6);
    int lane = threadIdx.x & 63;
    float2 v = *reinterpret_cast<const float2*>(x + (size_t)row * DD + lane * 2);
    float ss = v.x * v.x + v.y * v.y;
#pragma unroll
    for (int o = 32; o >= 1; o >>= 1) ss += __shfl_xor(ss, o);
    float inv = 1.0f / fmaxf(sqrtf(ss), 1e-12f);
    float y0 = v.x * inv, y1 = v.y * inv;

    unsigned short h0 = f2bf(y0);             float r0 = y0 - bf2f(h0);
    unsigned short m0 = f2bf(r0);             float s0 = r0 - bf2f(m0);
    unsigned short l0 = f2bf(s0);
    unsigned short h1 = f2bf(y1);             float r1 = y1 - bf2f(h1);
    unsigned short m1 = f2bf(r1);             float s1 = r1 - bf2f(m1);
    unsigned short l1 = f2bf(s1);

    size_t o = (size_t)row * DD + lane * 2;
    *reinterpret_cast<unsigned int*>(ph + o) = (unsigned int)h0 | ((unsigned int)h1 << 16);
    *reinterpret_cast<unsigned int*>(pm + o) = (unsigned int)m0 | ((unsigned int)m1 << 16);
    *reinterpret_cast<unsigned int*>(pl + o) = (unsigned int)l0 | ((unsigned int)l1 << 16);
}

union SMem {
    struct {
        unsigned short Ah[128][40], Am[128][40], Al[128][40];
        unsigned short Bh[128][40], Bm[128][40], Bl[128][40];
    } s;                      // 61440 B (MFMA staging)
    float q[4][32][68];       // 34816 B (per-wave transpose scratch)
};

__device__ __forceinline__ void stage_plane(const unsigned short* __restrict__ g,
                                            unsigned short (*s)[40], int tid,
                                            size_t rowbase, int c) {
#pragma unroll
    for (int hh = 0; hh < 2; ++hh) {
        int u = tid + (hh << 8);
        int row = u >> 2, qq = u & 3;
        const float4 v = *reinterpret_cast<const float4*>(
            g + (rowbase + row) * DD + (c << 5) + (qq << 3));
        *reinterpret_cast<float4*>(&s[row][qq << 3]) = v;
    }
}

// ---- 2. sim = xn.xn^T via 6-limb MFMA, upper-tri tiles, full-sector stores
__global__ __launch_bounds__(256, 2) void k_sim(const unsigned short* __restrict__ ph,
                                                const unsigned short* __restrict__ pm,
                                                const unsigned short* __restrict__ pl,
                                                float* __restrict__ sim) {
    // XCD-chunked bijective swizzle: 1152 = 8 * 144
    int bid = blockIdx.x;
    int lb  = (bid & 7) * 144 + (bid >> 3);
    int bl  = lb / 36;
    int p   = lb - bl * 36;
    int ti = 0;
    while (p >= 8 - ti) { p -= 8 - ti; ++ti; }
    int tj = ti + p;
    int R  = ti << 7, Cc = tj << 7;

    __shared__ SMem sm;

    int tid  = threadIdx.x;
    int wv   = tid >> 6;
    int lane = tid & 63;
    int wr = (wv >> 1) << 6;
    int wc = (wv & 1) << 6;
    int lg = lane >> 4, fr = lane & 15;

    size_t base = (size_t)bl * NN;
    size_t rbA = base + R, rbB = base + Cc;

    f32x4 acc[4][4];
#pragma unroll
    for (int i = 0; i < 4; ++i)
#pragma unroll
        for (int j = 0; j < 4; ++j) acc[i][j] = (f32x4){0.f, 0.f, 0.f, 0.f};

    int kk = lg << 3;

    for (int c = 0; c < 4; ++c) {
        if (c) __syncthreads();
        stage_plane(ph, sm.s.Ah, tid, rbA, c);
        stage_plane(pm, sm.s.Am, tid, rbA, c);
        stage_plane(pl, sm.s.Al, tid, rbA, c);
        stage_plane(ph, sm.s.Bh, tid, rbB, c);
        stage_plane(pm, sm.s.Bm, tid, rbB, c);
        stage_plane(pl, sm.s.Bl, tid, rbB, c);
        __syncthreads();

        bf16x8 bh[4], bm[4], blo[4];
#pragma unroll
        for (int cp = 0; cp < 4; ++cp) {
            int rb = wc + cp * 16 + fr;
            bh[cp]  = *reinterpret_cast<const bf16x8*>(&sm.s.Bh[rb][kk]);
            bm[cp]  = *reinterpret_cast<const bf16x8*>(&sm.s.Bm[rb][kk]);
            blo[cp] = *reinterpret_cast<const bf16x8*>(&sm.s.Bl[rb][kk]);
        }
#pragma unroll
        for (int rp = 0; rp < 4; ++rp) {
            int ra = wr + rp * 16 + fr;
            bf16x8 ah = *reinterpret_cast<const bf16x8*>(&sm.s.Ah[ra][kk]);
            bf16x8 am = *reinterpret_cast<const bf16x8*>(&sm.s.Am[ra][kk]);
            bf16x8 al = *reinterpret_cast<const bf16x8*>(&sm.s.Al[ra][kk]);
#pragma unroll
            for (int cp = 0; cp < 4; ++cp) {
                f32x4 cacc = acc[rp][cp];
                cacc = __builtin_amdgcn_mfma_f32_16x16x32_bf16(ah, bh[cp],  cacc, 0, 0, 0);
                cacc = __builtin_amdgcn_mfma_f32_16x16x32_bf16(ah, bm[cp],  cacc, 0, 0, 0);
                cacc = __builtin_amdgcn_mfma_f32_16x16x32_bf16(am, bh[cp],  cacc, 0, 0, 0);
                cacc = __builtin_amdgcn_mfma_f32_16x16x32_bf16(ah, blo[cp], cacc, 0, 0, 0);
                cacc = __builtin_amdgcn_mfma_f32_16x16x32_bf16(al, bh[cp],  cacc, 0, 0, 0);
                cacc = __builtin_amdgcn_mfma_f32_16x16x32_bf16(am, bm[cp],  cacc, 0, 0, 0);
                acc[rp][cp] = cacc;
            }
        }
    }

    __syncthreads();   // staging LDS dead -> reuse union as per-wave q[]
    float (*q)[68] = sm.q[wv];
    float* Cb = sim + base * NN;

    // ---- mirror block (tj,ti): transpose to q[col][row], 1KB stores ------
    if (ti != tj) {
#pragma unroll
        for (int hp = 0; hp < 2; ++hp) {
#pragma unroll
            for (int rp = 0; rp < 4; ++rp)
#pragma unroll
                for (int cpl = 0; cpl < 2; ++cpl) {
                    const f32x4 a = acc[rp][2 * hp + cpl];
                    *reinterpret_cast<float4*>(&q[cpl * 16 + fr][rp * 16 + lg * 4]) =
                        make_float4(a[0], a[1], a[2], a[3]);
                }
#pragma unroll
            for (int it = 0; it < 8; ++it) {
                int lcol = lg + 4 * it;
                const float4 v = *reinterpret_cast<const float4*>(&q[lcol][fr * 4]);
                *reinterpret_cast<float4*>(
                    &Cb[(size_t)(Cc + wc + 32 * hp + lcol) * NN + R + wr + fr * 4]) = v;
            }
        }
    }
    // ---- row block (ti,tj): transpose to q[row][col], 1KB stores ---------
#pragma unroll
    for (int hr = 0; hr < 2; ++hr) {
#pragma unroll
        for (int rpl = 0; rpl < 2; ++rpl)
#pragma unroll
            for (int cp = 0; cp < 4; ++cp)
#pragma unroll
                for (int reg = 0; reg < 4; ++reg)
                    q[rpl * 16 + lg * 4 + reg][cp * 16 + fr] = acc[2 * hr + rpl][cp][reg];
#pragma unroll
        for (int it = 0; it < 8; ++it) {
            int lrow = lg + 4 * it;
            const float4 v = *reinterpret_cast<const float4*>(&q[lrow][fr * 4]);
            *reinterpret_cast<float4*>(
                &Cb[(size_t)(R + wr + 32 * hr + lrow) * NN + Cc + wc + fr * 4]) = v;
        }
    }
}

// ---------------- 3. top-5 per row (wave per row) ------------------------
__global__ __launch_bounds__(256) void k_topk(const float* __restrict__ sim,
                                              int* __restrict__ idx) {
    int lrow = blockIdx.x * 4 + (threadIdx.x >> 6);
    int lane = threadIdx.x & 63;
    const float* sr = sim + (size_t)lrow * NN;
    int i = lrow & (NN - 1);

    float v[16];
#pragma unroll
    for (int q = 0; q < 4; ++q) {
        float4 f = *reinterpret_cast<const float4*>(sr + lane * 16 + q * 4);
        v[q * 4 + 0] = f.x; v[q * 4 + 1] = f.y; v[q * 4 + 2] = f.z; v[q * 4 + 3] = f.w;
    }
    if ((i >> 4) == lane) {
        int s = i & 15;
#pragma unroll
        for (int j = 0; j < 16; ++j) if (j == s) v[j] = -FLT_MAX;
    }
    int* op = idx + (size_t)lrow * KK;
#pragma unroll
    for (int t = 0; t < KK; ++t) {
        float bv = v[0]; int bj = 0;
#pragma unroll
        for (int j = 1; j < 16; ++j) if (v[j] > bv) { bv = v[j]; bj = j; }
        int bm = (lane << 4) + bj;
#pragma unroll
        for (int o = 1; o < 64; o <<= 1) {
            float ov = __shfl_xor(bv, o);
            int   om = __shfl_xor(bm, o);
            if (ov > bv || (ov == bv && om < bm)) { bv = ov; bm = om; }
        }
        if ((bm >> 4) == lane) {
            int s = bm & 15;
#pragma unroll
            for (int j = 0; j < 16; ++j) if (j == s) v[j] = -FLT_MAX;
        }
        if (lane == 0) op[t] = bm;
    }
}

// ---- 4. fused gcn: out = res + relu( agg(h,idx) @ W^T + bias ) ----------
// gather aggregated 64 full rows ONCE into As; W chunked BK=32 k-major.
#define SW(c) ((c) + 4 * ((c) >> 5))

__global__ __launch_bounds__(256, 3) void k_gcn(const float* __restrict__ h,
                                                const int* __restrict__ idx,
                                                const float* __restrict__ W,
                                                const float* __restrict__ bias,
                                                const float* __restrict__ res,
                                                float* __restrict__ out) {
    int rt = blockIdx.x << 6;
    __shared__ float As[64][132];
    __shared__ float Bs[32][140];
    int tid = threadIdx.x;

    {   // gather + aggregate full rows (48 independent float4 loads)
        int row = tid >> 2, fq = tid & 3;
        int grow = rt + row;
        const int* ip = idx + (size_t)grow * KK;
        const float* hb = h + (((size_t)grow >> 10) << 10) * DD;
        const float* hs = h + (size_t)grow * DD;
        int n0 = ip[0], n1 = ip[1], n2 = ip[2], n3 = ip[3], n4 = ip[4];
        const float* p0 = hb + (size_t)n0 * DD;
        const float* p1 = hb + (size_t)n1 * DD;
        const float* p2 = hb + (size_t)n2 * DD;
        const float* p3 = hb + (size_t)n3 * DD;
        const float* p4 = hb + (size_t)n4 * DD;
        const float cc = 1.0f / 6.0f;
#pragma unroll
        for (int rep = 0; rep < 8; ++rep) {
            int c = rep * 16 + fq * 4;
            float4 v  = *reinterpret_cast<const float4*>(hs + c);
            float4 u0 = *reinterpret_cast<const float4*>(p0 + c);
            float4 u1 = *reinterpret_cast<const float4*>(p1 + c);
            float4 u2 = *reinterpret_cast<const float4*>(p2 + c);
            float4 u3 = *reinterpret_cast<const float4*>(p3 + c);
            float4 u4 = *reinterpret_cast<const float4*>(p4 + c);
            v.x = (v.x + u0.x + u1.x + u2.x + u3.x + u4.x) * cc;
            v.y = (v.y + u0.y + u1.y + u2.y + u3.y + u4.y) * cc;
            v.z = (v.z + u0.z + u1.z + u2.z + u3.z + u4.z) * cc;
            v.w = (v.w + u0.w + u1.w + u2.w + u3.w + u4.w) * cc;
            *reinterpret_cast<float4*>(&As[row][c]) = v;
        }
    }

    int tr  = (tid >> 4) << 2;
    int tc  = (tid & 15) << 3;
    int stc = SW(tc);

    float acc[4][8];
#pragma unroll
    for (int i = 0; i < 4; ++i)
#pragma unroll
        for (int j = 0; j < 8; ++j) acc[i][j] = 0.f;

    for (int kc = 0; kc < 4; ++kc) {
        __syncthreads();          // As ready (kc=0) / Bs consumers done (kc>0)
        {   // stage W chunk k-major into Bs[k][SW(hcol)]
            int hcol = tid >> 1, kq = tid & 1;
            int swc = SW(hcol);
#pragma unroll
            for (int rep = 0; rep < 4; ++rep) {
                int f4i = rep * 2 + kq;
                const float4 v = *reinterpret_cast<const float4*>(
                    W + (size_t)hcol * DD + kc * 32 + f4i * 4);
                int k = f4i * 4;
                Bs[k + 0][swc] = v.x; Bs[k + 1][swc] = v.y;
                Bs[k + 2][swc] = v.z; Bs[k + 3][swc] = v.w;
            }
        }
        __syncthreads();
#pragma unroll 4
        for (int k = 0; k < 32; ++k) {
            int ck = kc * 32 + k;
            const float av[4] = {As[tr + 0][ck], As[tr + 1][ck],
                                 As[tr + 2][ck], As[tr + 3][ck]};
            const float4 b0 = *reinterpret_cast<const float4*>(&Bs[k][stc]);
            const float4 b1 = *reinterpret_cast<const float4*>(&Bs[k][stc + 4]);
            const float bw[8] = {b0.x, b0.y, b0.z, b0.w, b1.x, b1.y, b1.z, b1.w};
#pragma unroll
            for (int ii = 0; ii < 4; ++ii)
#pragma unroll
                for (int jj = 0; jj < 8; ++jj)
                    acc[ii][jj] = fmaf(av[ii], bw[jj], acc[ii][jj]);
        }
    }
    const float4 bz0 = *reinterpret_cast<const float4*>(bias + tc);
    const float4 bz1 = *reinterpret_cast<const float4*>(bias + tc + 4);
    const float bb[8] = {bz0.x, bz0.y, bz0.z, bz0.w, bz1.x, bz1.y, bz1.z, bz1.w};
#pragma unroll
    for (int i = 0; i < 4; ++i) {
        size_t ro = (size_t)(rt + tr + i) * DD + tc;
        const float4 r0 = *reinterpret_cast<const float4*>(res + ro);
        const float4 r1 = *reinterpret_cast<const float4*>(res + ro + 4);
        float4 o0, o1;
        o0.x = r0.x + fmaxf(acc[i][0] + bb[0], 0.f);
        o0.y = r0.y + fmaxf(acc[i][1] + bb[1], 0.f);
        o0.z = r0.z + fmaxf(acc[i][2] + bb[2], 0.f);
        o0.w = r0.w + fmaxf(acc[i][3] + bb[3], 0.f);
        o1.x = r1.x + fmaxf(acc[i][4] + bb[4], 0.f);
        o1.y = r1.y + fmaxf(acc[i][5] + bb[5], 0.f);
        o1.z = r1.z + fmaxf(acc[i][6] + bb[6], 0.f);
        o1.w = r1.w + fmaxf(acc[i][7] + bb[7], 0.f);
        *reinterpret_cast<float4*>(out + ro)     = o0;
        *reinterpret_cast<float4*>(out + ro + 4) = o1;
    }
}

extern "C" void kernel_launch(void* const* d_in, const int* in_sizes, int n_in,
                              void* d_out, int out_size, void* d_ws, size_t ws_size,
                              hipStream_t stream) {
    const float* x  = (const float*)d_in[0];
    const float* W1 = (const float*)d_in[1];
    const float* b1 = (const float*)d_in[2];
    const float* W2 = (const float*)d_in[3];
    const float* b2 = (const float*)d_in[4];
    float* out = (float*)d_out;

    char* ws = (char*)d_ws;
    size_t pl_b  = (size_t)BB * NN * DD * 2;
    size_t h1_b  = (size_t)BB * NN * DD * 4;
    size_t idx_b = (size_t)BB * NN * KK * 4;
    unsigned short* ph = (unsigned short*)ws;  ws += pl_b;
    unsigned short* pm = (unsigned short*)ws;  ws += pl_b;
    unsigned short* pl = (unsigned short*)ws;  ws += pl_b;
    float* h1  = (float*)ws;                   ws += h1_b;
    int*   idx = (int*)ws;                     ws += idx_b;
    float* sim = (float*)ws;   // 134 MB; ws_size >= 190 MB confirmed (r5 ran SB=32)

    k_norm<<<BB * NN / 4, 256, 0, stream>>>(x, ph, pm, pl);
    k_sim<<<BB * 36, 256, 0, stream>>>(ph, pm, pl, sim);
    k_topk<<<BB * NN / 4, 256, 0, stream>>>(sim, idx);
    k_gcn<<<BB * NN / 64, 256, 0, stream>>>(x,  idx, W1, b1, x,  h1);
    k_gcn<<<BB * NN / 64, 256, 0, stream>>>(h1, idx, W2, b2, h1, out);
}